// Round 1
// baseline (193.319 us; speedup 1.0000x reference)
//
#include <hip/hip_runtime.h>

// 2D CDF 5/3 lifting wavelet, fused one-kernel version.
// Input  x : (24, 1024, 1024) fp32   (24 = 8 batch * 3 ch)
// Output out: (8, 12, 512, 512) fp32, channel planes ordered LL(0..2) LH(3..5) HL(6..8) HH(9..11)
//
// Per block: 32x32 half-res output tile. Input region 72x72 (4-px halo each side).
// Phase 1: global -> LDS (edge-clamped; clamped slots provably never read).
// Phase 2: horizontal lifting (d then s) into LDS.
// Phase 3: vertical lifting per output element in registers, 4 coalesced stores.

static __device__ __forceinline__ int mref(int k) {
    // _rpad reflect in half-res index space (H = 512): e[-1]->E[1], e[H]->E[H-2]
    if (k < 0) return 1;
    if (k > 511) return 510;
    return k;
}

__global__ __launch_bounds__(256) void ilwt53_fused(const float* __restrict__ x,
                                                    float* __restrict__ out) {
    const int tid = threadIdx.x;
    const int c0  = blockIdx.x * 32;   // half-res col origin
    const int r0  = blockIdx.y * 32;   // half-res row origin
    const int img = blockIdx.z;        // b*3 + ch

    const int cb = 2 * c0 - 4;         // full-res col base of LDS tile
    const int rb = 2 * r0 - 4;         // full-res row base of LDS tile

    __shared__ float xt[72 * 73];      // input tile, stride 73 (odd -> no bank conflicts)
    __shared__ float db[72 * 35];      // horizontal detail, cols c0-1 .. c0+32 (j = c-c0+1)
    __shared__ float sb[72 * 33];      // horizontal smooth, cols c0 .. c0+31

    const float* __restrict__ xim = x + (size_t)img * (1024 * 1024);

    // ---- Phase 1: load 72x72 input tile, edge-clamped ----
    #pragma unroll
    for (int n = 0; n < 21; ++n) {
        int i = tid + n * 256;
        if (i < 72 * 72) {
            int lr = i / 72, lc = i - lr * 72;
            int gy = rb + lr; gy = gy < 0 ? 0 : (gy > 1023 ? 1023 : gy);
            int gx = cb + lc; gx = gx < 0 ? 0 : (gx > 1023 ? 1023 : gx);
            xt[lr * 73 + lc] = xim[(size_t)gy * 1024 + gx];
        }
    }
    __syncthreads();

    // ---- Phase 2a: horizontal detail d[c] = O[c] - 0.5*(E[m(c-1)] + E[m(c+1)]) ----
    // c in [c0-1, c0+32]; E[k] at local col 2*(k-c0)+4, O[c] at 2*(c-c0)+5
    for (int n = 0; n < 10; ++n) {
        int i = tid + n * 256;
        if (i < 72 * 34) {
            int lr = i / 34, j = i - lr * 34;
            int c = c0 - 1 + j;
            int km1 = mref(c - 1), kp1 = mref(c + 1);
            const float* row = xt + lr * 73;
            float o  = row[2 * (c - c0) + 5];
            float em = row[2 * (km1 - c0) + 4];
            float ep = row[2 * (kp1 - c0) + 4];
            db[lr * 35 + j] = o - 0.5f * (em + ep);
        }
    }
    __syncthreads();

    // ---- Phase 2b: horizontal smooth s[c] = E[c] + 0.25*(d[m(c-1)] + d[m(c+1)]) ----
    #pragma unroll
    for (int n = 0; n < 9; ++n) {              // 72*32 == 9*256 exactly
        int i = tid + n * 256;
        int lr = i / 32, jj = i & 31;
        int c = c0 + jj;
        int km1 = mref(c - 1), kp1 = mref(c + 1);
        float e  = xt[lr * 73 + 2 * jj + 4];
        float dm = db[lr * 35 + (km1 - c0 + 1)];
        float dp = db[lr * 35 + (kp1 - c0 + 1)];
        sb[lr * 33 + jj] = e + 0.25f * (dm + dp);
    }
    __syncthreads();

    // ---- Phase 3: vertical lifting + store ----
    const size_t plane = 512 * 512;
    float* __restrict__ ob = out + ((size_t)(img / 3) * 12 + (img % 3)) * plane;

    #pragma unroll
    for (int p = 0; p < 4; ++p) {
        int i  = tid + p * 256;
        int rr = i >> 5, cc = i & 31;
        int r = r0 + rr, c = c0 + cc;

        const float* sc = sb + cc;       // column base, row stride 33
        const float* dc = db + cc + 1;   // column base, row stride 35

        // half-res vertical index k -> local LDS row: even 2*(k-r0)+4, odd 2*(k-r0)+5
        auto SE = [&](int k) { return sc[(2 * (k - r0) + 4) * 33]; };
        auto SO = [&](int k) { return sc[(2 * (k - r0) + 5) * 33]; };
        auto DE = [&](int k) { return dc[(2 * (k - r0) + 4) * 35]; };
        auto DO = [&](int k) { return dc[(2 * (k - r0) + 5) * 35]; };

        auto LHf = [&](int k) { return SO(k) - 0.5f * (SE(mref(k - 1)) + SE(mref(k + 1))); };
        auto HHf = [&](int k) { return DO(k) - 0.5f * (DE(mref(k - 1)) + DE(mref(k + 1))); };

        int km = mref(r - 1), kp = mref(r + 1);

        float lh = LHf(r);
        float ll = SE(r) + 0.25f * (LHf(km) + LHf(kp));
        float hh = HHf(r);
        float hl = DE(r) + 0.25f * (HHf(km) + HHf(kp));

        size_t o = (size_t)r * 512 + c;
        ob[o]             = ll;
        ob[o + 3 * plane] = lh;
        ob[o + 6 * plane] = hl;
        ob[o + 9 * plane] = hh;
    }
}

extern "C" void kernel_launch(void* const* d_in, const int* in_sizes, int n_in,
                              void* d_out, int out_size, void* d_ws, size_t ws_size,
                              hipStream_t stream) {
    const float* x = (const float*)d_in[0];
    float* out = (float*)d_out;
    dim3 grid(16, 16, 24);   // 16x16 tiles per image, 24 images
    dim3 block(256);
    hipLaunchKernelGGL(ilwt53_fused, grid, block, 0, stream, x, out);
}

// Round 2
// 177.282 us; speedup vs baseline: 1.0905x; 1.0905x over previous
//
#include <hip/hip_runtime.h>

// 2D CDF 5/3 lifting wavelet, fused, register-horizontal + LDS-vertical version.
// Input  x : (24, 1024, 1024) fp32. Output: (8, 12, 512, 512) fp32,
// planes ordered LL(0..2) LH(3..5) HL(6..8) HH(9..11).
//
// Per block: 32x32 half-res tile.
// Phase A: each item loads a 24-float row window from global (float4),
//          computes horizontal d,s in registers, writes 8 s + 8 d via b128.
// Phase B1: LH/HH rows (34x32 each) computed once into LDS, all b128.
// Phase B2: one vector item/thread: 8 b128 reads -> 4 float4 global stores.

static __device__ __forceinline__ int mref(int k) {
    // _rpad reflect in half-res index space (N=512): e[-1]->E[1], e[512]->E[510]
    return k < 0 ? 1 : (k > 511 ? 510 : k);
}

__global__ __launch_bounds__(256) void ilwt53_v2(const float* __restrict__ x,
                                                 float* __restrict__ out) {
    const int tid = threadIdx.x;
    const int c0  = blockIdx.x * 32;   // half-res col origin
    const int r0  = blockIdx.y * 32;   // half-res row origin
    const int img = blockIdx.z;        // b*3 + ch
    const int rb  = 2 * r0 - 4;        // full-res row base (4-row halo)

    // row stride 36 floats: keeps b128 alignment (mult of 4) and offsets bank phases
    __shared__ float sS[72 * 36];      // horizontal smooth, full-res row lr, cols c0..c0+31
    __shared__ float sD[72 * 36];      // horizontal detail, same layout
    __shared__ float sLH[34 * 36];     // vertical LH rows, j = k-(r0-1)
    __shared__ float sHH[34 * 36];     // vertical HH rows

    const float* __restrict__ xim = x + (size_t)img * (1024 * 1024);

    // ---- Phase A: global -> registers (horizontal lifting) -> LDS ----
    // 72 rows x 4 col-groups = 288 items; item owns half-res cols c..c+7.
    #pragma unroll
    for (int it = 0; it < 2; ++it) {
        int i = tid + it * 256;
        if (i < 288) {
            int lr = i >> 2, g = i & 3;
            int gy = rb + lr; gy = gy < 0 ? 0 : (gy > 1023 ? 1023 : gy);
            const float* __restrict__ row = xim + (size_t)gy * 1024;
            int c  = c0 + 8 * g;       // first owned half-res col
            int fb = 2 * c - 4;        // 24-float full-res window base (16B aligned)

            float w[24];
            if (fb >= 0 && fb + 23 <= 1023) {
                const float4* p = (const float4*)(row + fb);
                #pragma unroll
                for (int q = 0; q < 6; ++q) {
                    float4 v = p[q];
                    w[4*q] = v.x; w[4*q+1] = v.y; w[4*q+2] = v.z; w[4*q+3] = v.w;
                }
            } else {
                #pragma unroll
                for (int q = 0; q < 24; ++q) {
                    int gx = fb + q; gx = gx < 0 ? 0 : (gx > 1023 ? 1023 : gx);
                    w[q] = row[gx];
                }
            }
            // window layout: E[c-2+u] = w[2u], O[c-2+u] = w[2u+1], u = 0..11
            // d[t] is global d[c-1+t], t = 0..9
            float d[10];
            #pragma unroll
            for (int t = 0; t < 10; ++t)
                d[t] = w[2*t+3] - 0.5f * (w[2*t] + w[2*t+4]);
            // horizontal image-edge fixes: d[0] = O[0]-E[1]; d[511] = O[511]-E[510]
            if (c == 0)   d[1] = w[5]  - w[6];    // global j=0  (t=1)
            if (c == 504) d[8] = w[19] - w[16];   // global j=511 (t=8)

            float s[8];
            #pragma unroll
            for (int i2 = 0; i2 < 8; ++i2)
                s[i2] = w[2*i2+4] + 0.25f * (d[i2] + d[i2+2]);
            // s edge fixes: s[0] uses d[m(-1)]=d[1] twice; s[511] uses d[510] twice
            if (c == 0)   s[0] = w[4]  + 0.5f * d[2];   // d[2] is global d[1]
            if (c == 504) s[7] = w[18] + 0.5f * d[7];   // d[7] is global d[510]

            float4* ps = (float4*)(sS + lr * 36 + 8 * g);
            ps[0] = make_float4(s[0], s[1], s[2], s[3]);
            ps[1] = make_float4(s[4], s[5], s[6], s[7]);
            float4* pd = (float4*)(sD + lr * 36 + 8 * g);
            pd[0] = make_float4(d[1], d[2], d[3], d[4]);   // global d[c..c+3]
            pd[1] = make_float4(d[5], d[6], d[7], d[8]);   // global d[c+4..c+7]
        }
    }
    __syncthreads();

    // ---- Phase B1: LH/HH rows into LDS ----
    // 34 k-rows x 8 col-groups = 272 items; each computes LH and HH for 4 cols.
    #pragma unroll
    for (int it = 0; it < 2; ++it) {
        int i = tid + it * 256;
        if (i < 272) {
            int j = i >> 3, ccg = i & 7;
            int k  = r0 - 1 + j;
            int km = mref(k - 1), kp = mref(k + 1);
            int lo = 2 * (k  - r0) + 5;   // SO(k) local full-res row
            int lm = 2 * (km - r0) + 4;   // SE(km)
            int lp = 2 * (kp - r0) + 4;   // SE(kp)
            int co = 4 * ccg;
            float4 so  = *(const float4*)(sS + lo * 36 + co);
            float4 sem = *(const float4*)(sS + lm * 36 + co);
            float4 sep = *(const float4*)(sS + lp * 36 + co);
            float4 dv  = *(const float4*)(sD + lo * 36 + co);
            float4 dem = *(const float4*)(sD + lm * 36 + co);
            float4 dep = *(const float4*)(sD + lp * 36 + co);
            float4 lh, hh;
            lh.x = so.x - 0.5f * (sem.x + sep.x);
            lh.y = so.y - 0.5f * (sem.y + sep.y);
            lh.z = so.z - 0.5f * (sem.z + sep.z);
            lh.w = so.w - 0.5f * (sem.w + sep.w);
            hh.x = dv.x - 0.5f * (dem.x + dep.x);
            hh.y = dv.y - 0.5f * (dem.y + dep.y);
            hh.z = dv.z - 0.5f * (dem.z + dep.z);
            hh.w = dv.w - 0.5f * (dem.w + dep.w);
            *(float4*)(sLH + j * 36 + co) = lh;
            *(float4*)(sHH + j * 36 + co) = hh;
        }
    }
    __syncthreads();

    // ---- Phase B2: LL/HL + gather, 4 float4 stores ----
    {
        int rr = tid >> 3, ccg = tid & 7;
        int r  = r0 + rr;
        int km = mref(r - 1), kp = mref(r + 1);
        int jm = km - (r0 - 1), jc = rr + 1, jp = kp - (r0 - 1);
        int le = 2 * rr + 4;              // SE(r)/DE(r) local full-res row
        int co = 4 * ccg;
        float4 se  = *(const float4*)(sS  + le * 36 + co);
        float4 de  = *(const float4*)(sD  + le * 36 + co);
        float4 lhm = *(const float4*)(sLH + jm * 36 + co);
        float4 lhc = *(const float4*)(sLH + jc * 36 + co);
        float4 lhp = *(const float4*)(sLH + jp * 36 + co);
        float4 hhm = *(const float4*)(sHH + jm * 36 + co);
        float4 hhc = *(const float4*)(sHH + jc * 36 + co);
        float4 hhp = *(const float4*)(sHH + jp * 36 + co);
        float4 ll, hl;
        ll.x = se.x + 0.25f * (lhm.x + lhp.x);
        ll.y = se.y + 0.25f * (lhm.y + lhp.y);
        ll.z = se.z + 0.25f * (lhm.z + lhp.z);
        ll.w = se.w + 0.25f * (lhm.w + lhp.w);
        hl.x = de.x + 0.25f * (hhm.x + hhp.x);
        hl.y = de.y + 0.25f * (hhm.y + hhp.y);
        hl.z = de.z + 0.25f * (hhm.z + hhp.z);
        hl.w = de.w + 0.25f * (hhm.w + hhp.w);

        const size_t plane = 512 * 512;
        float* __restrict__ ob = out + ((size_t)(img / 3) * 12 + (img % 3)) * plane;
        size_t o = (size_t)r * 512 + c0 + co;
        *(float4*)(ob + o)             = ll;
        *(float4*)(ob + o + 3 * plane) = lhc;
        *(float4*)(ob + o + 6 * plane) = hl;
        *(float4*)(ob + o + 9 * plane) = hhc;
    }
}

extern "C" void kernel_launch(void* const* d_in, const int* in_sizes, int n_in,
                              void* d_out, int out_size, void* d_ws, size_t ws_size,
                              hipStream_t stream) {
    const float* x = (const float*)d_in[0];
    float* out = (float*)d_out;
    dim3 grid(16, 16, 24);   // 16x16 half-res tiles per image, 24 images
    dim3 block(256);
    hipLaunchKernelGGL(ilwt53_v2, grid, block, 0, stream, x, out);
}